// Round 3
// baseline (302.311 us; speedup 1.0000x reference)
//
#include <hip/hip_runtime.h>
#include <hip/hip_bf16.h>

typedef __bf16 bf16x8 __attribute__((ext_vector_type(8)));
typedef float  f32x4  __attribute__((ext_vector_type(4)));

static constexpr int S  = 64;    // DIM_S
static constexpr int C  = 8;     // DIM_C (experts)
static constexpr int HD = 256;   // hidden width

__device__ __forceinline__ unsigned short f2bf(float f) {
  __hip_bfloat16 b = __float2bfloat16(f);
  unsigned short u;
  __builtin_memcpy(&u, &b, 2);
  return u;
}

// LDS-tiled transposes, coalesced both sides.
// blocks 0..511:  W2 [C][256k][256n] -> W2T bf16 [C][256n][256k]  (64 tiles/expert)
// blocks 512..639: W1 [C][64s][256h] -> W1T bf16 [C][256h][64s]   (16 tiles/expert)
__global__ __launch_bounds__(256) void prep_weights(
    const float* __restrict__ W1, const float* __restrict__ W2,
    unsigned short* __restrict__ W1T, unsigned short* __restrict__ W2T)
{
  __shared__ float tile[32][33];
  const int tid = threadIdx.x, cl = tid & 31, r0 = tid >> 5;
  const int b = blockIdx.x;
  if (b < 512) {
    const int c = b >> 6, t = b & 63, kt = t >> 3, nt = t & 7;
    const float* src = W2 + c * 65536;
    #pragma unroll
    for (int i = 0; i < 4; ++i) {
      int r = r0 + 8 * i;
      tile[r][cl] = src[(kt * 32 + r) * 256 + nt * 32 + cl];
    }
    __syncthreads();
    unsigned short* dst = W2T + c * 65536;
    #pragma unroll
    for (int i = 0; i < 4; ++i) {
      int r = r0 + 8 * i;
      dst[(nt * 32 + r) * 256 + kt * 32 + cl] = f2bf(tile[cl][r]);
    }
  } else {
    const int bb = b - 512;
    const int c = bb >> 4, t = bb & 15, st2 = t >> 3, ht = t & 7;
    const float* src = W1 + c * 16384;
    #pragma unroll
    for (int i = 0; i < 4; ++i) {
      int r = r0 + 8 * i;
      tile[r][cl] = src[(st2 * 32 + r) * 256 + ht * 32 + cl];
    }
    __syncthreads();
    unsigned short* dst = W1T + c * 16384;
    #pragma unroll
    for (int i = 0; i < 4; ++i) {
      int r = r0 + 8 * i;
      dst[(ht * 32 + r) * 64 + st2 * 32 + cl] = f2bf(tile[cl][r]);
    }
  }
}

// One block: 128 batch rows x 1 expert. 256 threads = 4 waves, 32 rows/wave.
// c = blockIdx>>9 (c-major): consecutive blocks share expert -> W1T/W2T L1/L2-hot.
// LDS = 18432 (sT transpose scratch) + 33792 (W2 ping-pong) = 52224 B -> 3 blocks/CU.
__global__ __launch_bounds__(256, 3) void moe_fused(
    const float* __restrict__ st,
    const unsigned short* __restrict__ W1T,
    const unsigned short* __restrict__ W2T,
    const float* __restrict__ b1,
    const float* __restrict__ b2,
    const float* __restrict__ W3,
    const float* __restrict__ b3,
    float* __restrict__ out)
{
  constexpr int LDT  = 72;   // sT pitch (64 + 8 pad bf16)
  constexpr int LDW2 = 264;  // W2 chunk pitch (256 + 8 pad bf16)
  constexpr int CH   = 32;   // W2 chunk rows

  __shared__ __align__(16) unsigned short sT[128 * LDT];      // 18432 B
  __shared__ __align__(16) unsigned short sW[2][CH * LDW2];   // 33792 B

  const int tid  = threadIdx.x;
  const int lane = tid & 63;
  const int wv   = tid >> 6;
  const int l15  = lane & 15;
  const int q    = lane >> 4;
  const int c    = blockIdx.x >> 9;
  const int row0 = (blockIdx.x & 511) * 128;

  const unsigned short* W1c = W1T + c * HD * S;
  const unsigned short* W2c = W2T + c * HD * HD;

  // ---- prefetch W2 chunk 0 (latency hidden behind all of phase 1) ----
  uint4 stg[4];
  {
    const uint4* src = reinterpret_cast<const uint4*>(W2c);
    #pragma unroll
    for (int i = 0; i < 4; ++i) stg[i] = src[tid + i * 256];
  }

  // ---- phase-1 A fragments straight from global st (fp32 -> bf16) ----
  bf16x8 aA[2][2];   // [rt][ks]
  #pragma unroll
  for (int rt = 0; rt < 2; ++rt)
    #pragma unroll
    for (int ks = 0; ks < 2; ++ks) {
      const int row = row0 + wv * 32 + rt * 16 + l15;
      const float4* p = reinterpret_cast<const float4*>(st + (size_t)row * S + ks * 32 + q * 8);
      float4 x = p[0], y = p[1];
      union { bf16x8 v; unsigned short u[8]; } a;
      a.u[0] = f2bf(x.x); a.u[1] = f2bf(x.y); a.u[2] = f2bf(x.z); a.u[3] = f2bf(x.w);
      a.u[4] = f2bf(y.x); a.u[5] = f2bf(y.y); a.u[6] = f2bf(y.z); a.u[7] = f2bf(y.w);
      aA[rt][ks] = a.v;
    }

  // ---- phase 1 in 4 quarters (64 cols each), B-frags direct from W1T ----
  // quarter cc -> h1 cols [cc*64, cc*64+64) -> aF[cc] A-fragments for phase 2
  bf16x8 aF[4][2][2];  // [cc][rt][k2]
  #pragma unroll
  for (int cc = 0; cc < 4; ++cc) {
    f32x4 acc[2][4];
    #pragma unroll
    for (int rt = 0; rt < 2; ++rt)
      #pragma unroll
      for (int ctl = 0; ctl < 4; ++ctl)
        acc[rt][ctl] = (f32x4){0.f, 0.f, 0.f, 0.f};

    #pragma unroll
    for (int ks = 0; ks < 2; ++ks) {
      const int koff = ks * 32 + q * 8;
      #pragma unroll
      for (int ctl = 0; ctl < 4; ++ctl) {
        const int n = (cc * 4 + ctl) * 16 + l15;
        bf16x8 b = *reinterpret_cast<const bf16x8*>(W1c + n * S + koff);
        acc[0][ctl] = __builtin_amdgcn_mfma_f32_16x16x32_bf16(aA[0][ks], b, acc[0][ctl], 0, 0, 0);
        acc[1][ctl] = __builtin_amdgcn_mfma_f32_16x16x32_bf16(aA[1][ks], b, acc[1][ctl], 0, 0, 0);
      }
    }

    // bias+relu; C-layout -> A-layout through this wave's OWN sT rows.
    // Rows [wv*32, wv*32+32) are written AND read only by wave wv: no barrier,
    // just lgkmcnt drain (DS ops of one wave are processed in issue order).
    #pragma unroll
    for (int rt = 0; rt < 2; ++rt) {
      const int rbase = wv * 32 + rt * 16 + q * 4;
      #pragma unroll
      for (int ctl = 0; ctl < 4; ++ctl) {
        const float bias = b1[c * HD + (cc * 4 + ctl) * 16 + l15];
        #pragma unroll
        for (int r = 0; r < 4; ++r) {
          float v = acc[rt][ctl][r] + bias;
          v = v > 0.f ? v : 0.f;
          sT[(rbase + r) * LDT + ctl * 16 + l15] = f2bf(v);
        }
      }
    }
    __asm__ __volatile__("s_waitcnt lgkmcnt(0)" ::: "memory");
    #pragma unroll
    for (int rt = 0; rt < 2; ++rt)
      #pragma unroll
      for (int k2 = 0; k2 < 2; ++k2)
        aF[cc][rt][k2] = *reinterpret_cast<const bf16x8*>(
            sT + (wv * 32 + rt * 16 + l15) * LDT + k2 * 32 + q * 8);
    __asm__ __volatile__("s_waitcnt lgkmcnt(0)" ::: "memory");  // WAR guard for next cc
  }

  // ---- stage chunk 0 into ping buffer ----
  #pragma unroll
  for (int i = 0; i < 4; ++i) {
    int f = tid + i * 256;
    *reinterpret_cast<uint4*>(&sW[0][(f >> 5) * LDW2 + (f & 31) * 8]) = stg[i];
  }
  __syncthreads();

  // ---- phase 2+3: ping-pong chunks of 32 W2T rows; d never materializes h2 ----
  float dacc[2][4];
  #pragma unroll
  for (int rt = 0; rt < 2; ++rt)
    #pragma unroll
    for (int r = 0; r < 4; ++r) dacc[rt][r] = 0.f;

  #pragma unroll
  for (int ch = 0; ch < 8; ++ch) {
    if (ch < 7) {   // issue next chunk's global loads BEFORE compute (stay in flight)
      const uint4* src = reinterpret_cast<const uint4*>(W2c + (ch + 1) * CH * HD);
      #pragma unroll
      for (int i = 0; i < 4; ++i) stg[i] = src[tid + i * 256];
    }

    const unsigned short* buf = sW[ch & 1];
    f32x4 acc[2][2];
    #pragma unroll
    for (int rt = 0; rt < 2; ++rt)
      #pragma unroll
      for (int ct = 0; ct < 2; ++ct)
        acc[rt][ct] = (f32x4){0.f, 0.f, 0.f, 0.f};

    #pragma unroll
    for (int ks = 0; ks < 8; ++ks) {
      const int koff = ks * 32 + q * 8;
      const int cc = ks >> 1, k2 = ks & 1;
      #pragma unroll
      for (int ct = 0; ct < 2; ++ct) {
        bf16x8 b = *reinterpret_cast<const bf16x8*>(buf + (ct * 16 + l15) * LDW2 + koff);
        acc[0][ct] = __builtin_amdgcn_mfma_f32_16x16x32_bf16(aF[cc][0][k2], b, acc[0][ct], 0, 0, 0);
        acc[1][ct] = __builtin_amdgcn_mfma_f32_16x16x32_bf16(aF[cc][1][k2], b, acc[1][ct], 0, 0, 0);
      }
    }

    // fused epilogue: relu(h2 + b2) dot W3, accumulated per row
    #pragma unroll
    for (int ct = 0; ct < 2; ++ct) {
      const int n = ch * CH + ct * 16 + l15;
      const float bias = b2[c * HD + n];
      const float w3v  = W3[c * HD + n];
      #pragma unroll
      for (int rt = 0; rt < 2; ++rt)
        #pragma unroll
        for (int r = 0; r < 4; ++r) {
          float v = acc[rt][ct][r] + bias;
          v = v > 0.f ? v : 0.f;
          dacc[rt][r] += v * w3v;
        }
    }

    if (ch < 7) {   // write next chunk into the other buffer (safe: its readers
                    // finished at the barrier ending iteration ch-1)
      #pragma unroll
      for (int i = 0; i < 4; ++i) {
        int f = tid + i * 256;
        *reinterpret_cast<uint4*>(&sW[(ch + 1) & 1][(f >> 5) * LDW2 + (f & 31) * 8]) = stg[i];
      }
    }
    __syncthreads();
  }

  // ---- reduce over the 16 col-lanes, write out ----
  #pragma unroll
  for (int rt = 0; rt < 2; ++rt)
    #pragma unroll
    for (int r = 0; r < 4; ++r) {
      float v = dacc[rt][r];
      v += __shfl_xor(v, 1);
      v += __shfl_xor(v, 2);
      v += __shfl_xor(v, 4);
      v += __shfl_xor(v, 8);
      dacc[rt][r] = v;
    }

  if (l15 == 0) {
    const float bb = b3[c];
    const int rbase = row0 + wv * 32 + q * 4;
    #pragma unroll
    for (int rt = 0; rt < 2; ++rt)
      #pragma unroll
      for (int r = 0; r < 4; ++r)
        out[(rbase + rt * 16 + r) * C + c] = dacc[rt][r] + bb;
  }
}

extern "C" void kernel_launch(void* const* d_in, const int* in_sizes, int n_in,
                              void* d_out, int out_size, void* d_ws, size_t ws_size,
                              hipStream_t stream)
{
  const float* st = (const float*)d_in[0];
  const float* W1 = (const float*)d_in[1];
  const float* b1 = (const float*)d_in[2];
  const float* W2 = (const float*)d_in[3];
  const float* b2 = (const float*)d_in[4];
  const float* W3 = (const float*)d_in[5];
  const float* b3 = (const float*)d_in[6];
  float* out = (float*)d_out;

  unsigned short* W1T = (unsigned short*)d_ws;         // 131072 bf16
  unsigned short* W2T = W1T + C * HD * S;              // 524288 bf16

  prep_weights<<<dim3(640), dim3(256), 0, stream>>>(W1, W2, W1T, W2T);
  moe_fused<<<dim3(4096), dim3(256), 0, stream>>>(st, W1T, W2T, b1, b2, W3, b3, out);
}

// Round 4
// 218.708 us; speedup vs baseline: 1.3823x; 1.3823x over previous
//
#include <hip/hip_runtime.h>
#include <hip/hip_bf16.h>

typedef __bf16 bf16x8 __attribute__((ext_vector_type(8)));
typedef float  f32x4  __attribute__((ext_vector_type(4)));

static constexpr int S  = 64;    // DIM_S
static constexpr int C  = 8;     // DIM_C (experts)
static constexpr int HD = 256;   // hidden width

__device__ __forceinline__ unsigned short f2bf(float f) {
  __hip_bfloat16 b = __float2bfloat16(f);
  unsigned short u;
  __builtin_memcpy(&u, &b, 2);
  return u;
}

// async global->LDS DMA, 16 B per lane; lds dest = wave-uniform base + lane*16
__device__ __forceinline__ void gl2lds16(const void* g, void* l) {
  __builtin_amdgcn_global_load_lds(
      (const __attribute__((address_space(1))) unsigned int*)g,
      (__attribute__((address_space(3))) unsigned int*)l, 16, 0, 0);
}

// LDS-tiled transposes, coalesced both sides.
// blocks 0..511:  W2 [C][256k][256n] -> W2T bf16 [C][256n][256k]
// blocks 512..639: W1 [C][64s][256h] -> W1T bf16 [C][256h][64s]
__global__ __launch_bounds__(256) void prep_weights(
    const float* __restrict__ W1, const float* __restrict__ W2,
    unsigned short* __restrict__ W1T, unsigned short* __restrict__ W2T)
{
  __shared__ float tile[32][33];
  const int tid = threadIdx.x, cl = tid & 31, r0 = tid >> 5;
  const int b = blockIdx.x;
  if (b < 512) {
    const int c = b >> 6, t = b & 63, kt = t >> 3, nt = t & 7;
    const float* src = W2 + c * 65536;
    #pragma unroll
    for (int i = 0; i < 4; ++i) {
      int r = r0 + 8 * i;
      tile[r][cl] = src[(kt * 32 + r) * 256 + nt * 32 + cl];
    }
    __syncthreads();
    unsigned short* dst = W2T + c * 65536;
    #pragma unroll
    for (int i = 0; i < 4; ++i) {
      int r = r0 + 8 * i;
      dst[(nt * 32 + r) * 256 + kt * 32 + cl] = f2bf(tile[cl][r]);
    }
  } else {
    const int bb = b - 512;
    const int c = bb >> 4, t = bb & 15, st2 = t >> 3, ht = t & 7;
    const float* src = W1 + c * 16384;
    #pragma unroll
    for (int i = 0; i < 4; ++i) {
      int r = r0 + 8 * i;
      tile[r][cl] = src[(st2 * 32 + r) * 256 + ht * 32 + cl];
    }
    __syncthreads();
    unsigned short* dst = W1T + c * 16384;
    #pragma unroll
    for (int i = 0; i < 4; ++i) {
      int r = r0 + 8 * i;
      dst[(ht * 32 + r) * 64 + st2 * 32 + cl] = f2bf(tile[cl][r]);
    }
  }
}

// One block: 128 batch rows x 1 expert. 256 threads = 4 waves, 32 rows/wave.
// c-major grid: blocks on a CU share the expert -> W1T L1-hot; st comes from L3.
// LDS: sT 18432 + sW2 32768 = 51200 B -> 3 blocks/CU (12 waves).
__global__ __launch_bounds__(256, 3) void moe_fused(
    const float* __restrict__ st,
    const unsigned short* __restrict__ W1T,
    const unsigned short* __restrict__ W2T,
    const float* __restrict__ b1,
    const float* __restrict__ b2,
    const float* __restrict__ W3,
    const float* __restrict__ b3,
    float* __restrict__ out)
{
  constexpr int LDT = 72;   // sT pitch (64 + 8 pad bf16); b128-aligned rows

  __shared__ __align__(16) unsigned short sT[128 * LDT];     // 18432 B
  // W2 ping-pong: 2 chunks x 32 rows x 256 bf16, NO pad (DMA-contiguous).
  // Swizzle: phys granule p = j ^ (row&7)  (granule = 8 bf16 = 16 B)
  __shared__ __align__(16) unsigned short sW2[2 * 32 * 256]; // 32768 B

  const int tid  = threadIdx.x;
  const int lane = tid & 63;
  const int wv   = tid >> 6;
  const int l15  = lane & 15;
  const int q    = lane >> 4;
  const int c    = blockIdx.x >> 9;
  const int row0 = (blockIdx.x & 511) * 128;

  const unsigned short* W1c = W1T + c * HD * S;
  const unsigned short* W2c = W2T + c * HD * HD;

  // ---- phase-1 A fragments straight from global st (fp32 -> bf16) ----
  bf16x8 aA[2][2];   // [rt][ks]
  #pragma unroll
  for (int rt = 0; rt < 2; ++rt)
    #pragma unroll
    for (int ks = 0; ks < 2; ++ks) {
      const int row = row0 + wv * 32 + rt * 16 + l15;
      const float4* p = reinterpret_cast<const float4*>(st + (size_t)row * S + ks * 32 + q * 8);
      float4 x = p[0], y = p[1];
      union { bf16x8 v; unsigned short u[8]; } a;
      a.u[0] = f2bf(x.x); a.u[1] = f2bf(x.y); a.u[2] = f2bf(x.z); a.u[3] = f2bf(x.w);
      a.u[4] = f2bf(y.x); a.u[5] = f2bf(y.y); a.u[6] = f2bf(y.z); a.u[7] = f2bf(y.w);
      aA[rt][ks] = a.v;
    }

  // ---- phase 1: 4 quarters of 64 cols; B-frags direct from W1T (L1-hot) ----
  bf16x8 aF[4][2][2];  // [cc][rt][k2] h1 A-fragments, register-resident
  #pragma unroll
  for (int cc = 0; cc < 4; ++cc) {
    f32x4 acc[2][4];
    #pragma unroll
    for (int rt = 0; rt < 2; ++rt)
      #pragma unroll
      for (int ctl = 0; ctl < 4; ++ctl)
        acc[rt][ctl] = (f32x4){0.f, 0.f, 0.f, 0.f};

    #pragma unroll
    for (int ks = 0; ks < 2; ++ks) {
      const int koff = ks * 32 + q * 8;
      #pragma unroll
      for (int ctl = 0; ctl < 4; ++ctl) {
        const int n = (cc * 4 + ctl) * 16 + l15;
        bf16x8 b = *reinterpret_cast<const bf16x8*>(W1c + n * S + koff);
        acc[0][ctl] = __builtin_amdgcn_mfma_f32_16x16x32_bf16(aA[0][ks], b, acc[0][ctl], 0, 0, 0);
        acc[1][ctl] = __builtin_amdgcn_mfma_f32_16x16x32_bf16(aA[1][ks], b, acc[1][ctl], 0, 0, 0);
      }
    }

    // bias+relu; C-layout -> A-layout through this wave's OWN sT rows
    // (rows [wv*32, wv*32+32) touched only by wave wv -> lgkmcnt drain, no barrier)
    #pragma unroll
    for (int rt = 0; rt < 2; ++rt) {
      const int rbase = wv * 32 + rt * 16 + q * 4;
      #pragma unroll
      for (int ctl = 0; ctl < 4; ++ctl) {
        const float bias = b1[c * HD + (cc * 4 + ctl) * 16 + l15];
        #pragma unroll
        for (int r = 0; r < 4; ++r) {
          float v = acc[rt][ctl][r] + bias;
          v = v > 0.f ? v : 0.f;
          sT[(rbase + r) * LDT + ctl * 16 + l15] = f2bf(v);
        }
      }
    }
    __asm__ __volatile__("s_waitcnt lgkmcnt(0)" ::: "memory");
    #pragma unroll
    for (int rt = 0; rt < 2; ++rt)
      #pragma unroll
      for (int k2 = 0; k2 < 2; ++k2)
        aF[cc][rt][k2] = *reinterpret_cast<const bf16x8*>(
            sT + (wv * 32 + rt * 16 + l15) * LDT + k2 * 32 + q * 8);
    __asm__ __volatile__("s_waitcnt lgkmcnt(0)" ::: "memory");  // WAR guard
  }

  // ---- DMA prologue: chunks 0,1 (issued AFTER phase-1 loads: vmcnt is FIFO) ----
  // chunk = 32 rows x 512 B = 16 KB = 16 x 1KB instrs; 4 per wave
  #pragma unroll
  for (int pc = 0; pc < 2; ++pc) {
    unsigned short* buf = sW2 + pc * (32 * 256);
    #pragma unroll
    for (int i = 0; i < 4; ++i) {
      const int b2 = wv * 4 + i;            // 1KB block 0..15 (2 rows each)
      const int r  = b2 * 2 + (lane >> 5);  // local row 0..31
      const int p  = lane & 31;             // phys granule
      const int j  = p ^ (r & 7);           // logical granule
      gl2lds16(W2c + (pc * 32 + r) * 256 + j * 8, buf + b2 * 512);
    }
  }
  __syncthreads();   // compiler drains vmcnt(0): chunks 0,1 landed, all waves ready

  // ---- phase 2+3: d = relu(h1 @ W2 + b2) . W3, chunk ping-pong ----
  float dacc[2][4];
  #pragma unroll
  for (int rt = 0; rt < 2; ++rt)
    #pragma unroll
    for (int r = 0; r < 4; ++r) dacc[rt][r] = 0.f;

  #pragma unroll
  for (int ch = 0; ch < 8; ++ch) {
    const unsigned short* buf = sW2 + (ch & 1) * (32 * 256);

    f32x4 acc[2][2];
    #pragma unroll
    for (int rt = 0; rt < 2; ++rt)
      #pragma unroll
      for (int ct = 0; ct < 2; ++ct)
        acc[rt][ct] = (f32x4){0.f, 0.f, 0.f, 0.f};

    #pragma unroll
    for (int ks = 0; ks < 8; ++ks) {
      const int jj = ks * 4 + q;            // logical granule of this k-slice
      const int cc = ks >> 1, k2 = ks & 1;
      #pragma unroll
      for (int ct = 0; ct < 2; ++ct) {
        const int nl = ct * 16 + l15;       // local row (= h2 col within chunk)
        bf16x8 b = *reinterpret_cast<const bf16x8*>(
            buf + nl * 256 + ((jj ^ (l15 & 7)) << 3));
        acc[0][ct] = __builtin_amdgcn_mfma_f32_16x16x32_bf16(aF[cc][0][k2], b, acc[0][ct], 0, 0, 0);
        acc[1][ct] = __builtin_amdgcn_mfma_f32_16x16x32_bf16(aF[cc][1][k2], b, acc[1][ct], 0, 0, 0);
      }
    }

    // fused epilogue: relu(h2 + b2) dot W3 per row
    #pragma unroll
    for (int ct = 0; ct < 2; ++ct) {
      const int n = ch * 32 + ct * 16 + l15;
      const float bias = b2[c * HD + n];
      const float w3v  = W3[c * HD + n];
      #pragma unroll
      for (int rt = 0; rt < 2; ++rt)
        #pragma unroll
        for (int r = 0; r < 4; ++r) {
          float v = acc[rt][ct][r] + bias;
          v = v > 0.f ? v : 0.f;
          dacc[rt][r] += v * w3v;
        }
    }

    __syncthreads();   // all waves done reading buf[ch&1]; drains in-flight DMA
    if (ch < 6) {      // refill the buffer just freed with chunk ch+2
      unsigned short* nbuf = sW2 + (ch & 1) * (32 * 256);
      #pragma unroll
      for (int i = 0; i < 4; ++i) {
        const int b2 = wv * 4 + i;
        const int r  = b2 * 2 + (lane >> 5);
        const int p  = lane & 31;
        const int j  = p ^ (r & 7);
        gl2lds16(W2c + ((ch + 2) * 32 + r) * 256 + j * 8, nbuf + b2 * 512);
      }
    }
  }

  // ---- reduce over the 16 col-lanes, write out ----
  #pragma unroll
  for (int rt = 0; rt < 2; ++rt)
    #pragma unroll
    for (int r = 0; r < 4; ++r) {
      float v = dacc[rt][r];
      v += __shfl_xor(v, 1);
      v += __shfl_xor(v, 2);
      v += __shfl_xor(v, 4);
      v += __shfl_xor(v, 8);
      dacc[rt][r] = v;
    }

  if (l15 == 0) {
    const float bb = b3[c];
    const int rbase = row0 + wv * 32 + q * 4;
    #pragma unroll
    for (int rt = 0; rt < 2; ++rt)
      #pragma unroll
      for (int r = 0; r < 4; ++r)
        out[(rbase + rt * 16 + r) * C + c] = dacc[rt][r] + bb;
  }
}

extern "C" void kernel_launch(void* const* d_in, const int* in_sizes, int n_in,
                              void* d_out, int out_size, void* d_ws, size_t ws_size,
                              hipStream_t stream)
{
  const float* st = (const float*)d_in[0];
  const float* W1 = (const float*)d_in[1];
  const float* b1 = (const float*)d_in[2];
  const float* W2 = (const float*)d_in[3];
  const float* b2 = (const float*)d_in[4];
  const float* W3 = (const float*)d_in[5];
  const float* b3 = (const float*)d_in[6];
  float* out = (float*)d_out;

  unsigned short* W1T = (unsigned short*)d_ws;         // 131072 bf16
  unsigned short* W2T = W1T + C * HD * S;              // 524288 bf16

  prep_weights<<<dim3(640), dim3(256), 0, stream>>>(W1, W2, W1T, W2T);
  moe_fused<<<dim3(4096), dim3(256), 0, stream>>>(st, W1T, W2T, b1, b2, W3, b3, out);
}

// Round 5
// 180.532 us; speedup vs baseline: 1.6746x; 1.2115x over previous
//
#include <hip/hip_runtime.h>
#include <hip/hip_bf16.h>

typedef __bf16 bf16x8 __attribute__((ext_vector_type(8)));
typedef float  f32x4  __attribute__((ext_vector_type(4)));

static constexpr int S  = 64;    // DIM_S
static constexpr int C  = 8;     // DIM_C (experts)
static constexpr int HD = 256;   // hidden width

__device__ __forceinline__ unsigned short f2bf(float f) {
  __hip_bfloat16 b = __float2bfloat16(f);
  unsigned short u;
  __builtin_memcpy(&u, &b, 2);
  return u;
}

// async global->LDS DMA, 16 B per lane; lds dest = wave-uniform base + lane*16
__device__ __forceinline__ void gl2lds16(const void* g, void* l) {
  __builtin_amdgcn_global_load_lds(
      (const __attribute__((address_space(1))) unsigned int*)g,
      (__attribute__((address_space(3))) unsigned int*)l, 16, 0, 0);
}

// LDS-tiled transposes, coalesced both sides.
// blocks 0..511:  W2 [C][256k][256n] -> W2T bf16 [C][256n][256k]
// blocks 512..639: W1 [C][64s][256h] -> W1T bf16 [C][256h][64s]
__global__ __launch_bounds__(256) void prep_weights(
    const float* __restrict__ W1, const float* __restrict__ W2,
    unsigned short* __restrict__ W1T, unsigned short* __restrict__ W2T)
{
  __shared__ float tile[32][33];
  const int tid = threadIdx.x, cl = tid & 31, r0 = tid >> 5;
  const int b = blockIdx.x;
  if (b < 512) {
    const int c = b >> 6, t = b & 63, kt = t >> 3, nt = t & 7;
    const float* src = W2 + c * 65536;
    #pragma unroll
    for (int i = 0; i < 4; ++i) {
      int r = r0 + 8 * i;
      tile[r][cl] = src[(kt * 32 + r) * 256 + nt * 32 + cl];
    }
    __syncthreads();
    unsigned short* dst = W2T + c * 65536;
    #pragma unroll
    for (int i = 0; i < 4; ++i) {
      int r = r0 + 8 * i;
      dst[(nt * 32 + r) * 256 + kt * 32 + cl] = f2bf(tile[cl][r]);
    }
  } else {
    const int bb = b - 512;
    const int c = bb >> 4, t = bb & 15, st2 = t >> 3, ht = t & 7;
    const float* src = W1 + c * 16384;
    #pragma unroll
    for (int i = 0; i < 4; ++i) {
      int r = r0 + 8 * i;
      tile[r][cl] = src[(st2 * 32 + r) * 256 + ht * 32 + cl];
    }
    __syncthreads();
    unsigned short* dst = W1T + c * 16384;
    #pragma unroll
    for (int i = 0; i < 4; ++i) {
      int r = r0 + 8 * i;
      dst[(ht * 32 + r) * 64 + st2 * 32 + cl] = f2bf(tile[cl][r]);
    }
  }
}

// One block: 256 batch rows x 1 expert. 4 waves, 64 rows/wave (4 row-tiles).
// c-major grid (c = blockIdx>>8): concurrent blocks share 1-2 experts -> W1T/W2T L2-hot.
// LDS: sT 36864 + sW2 32768 = 69632 B -> 2 blocks/CU. VGPR cap 256 (aF->AGPRs).
__global__ __launch_bounds__(256, 2) void moe_fused(
    const float* __restrict__ st,
    const unsigned short* __restrict__ W1T,
    const unsigned short* __restrict__ W2T,
    const float* __restrict__ b1,
    const float* __restrict__ b2,
    const float* __restrict__ W3,
    const float* __restrict__ b3,
    float* __restrict__ out)
{
  constexpr int LDT = 72;   // sT pitch (64 + 8 pad bf16); 144 B rows, 16B-aligned

  __shared__ __align__(16) unsigned short sT[256 * LDT];     // 36864 B
  // W2 ping-pong: 2 chunks x 32 rows x 256 bf16, NO pad (DMA-contiguous).
  // Swizzle: phys granule p = j ^ (row&7)  (granule = 8 bf16 = 16 B)
  __shared__ __align__(16) unsigned short sW2[2 * 32 * 256]; // 32768 B

  const int tid  = threadIdx.x;
  const int lane = tid & 63;
  const int wv   = tid >> 6;          // wave -> rows [wv*64, wv*64+64)
  const int l15  = lane & 15;
  const int q    = lane >> 4;
  const int c    = blockIdx.x >> 8;
  const int row0 = (blockIdx.x & 255) * 256;

  const unsigned short* W1c = W1T + c * HD * S;
  const unsigned short* W2c = W2T + c * HD * HD;

  // ---- A fragments straight from global st (fp32 -> bf16); issued FIRST ----
  bf16x8 aA[4][2];   // [rt][ks]
  #pragma unroll
  for (int rt = 0; rt < 4; ++rt)
    #pragma unroll
    for (int ks = 0; ks < 2; ++ks) {
      const int row = row0 + wv * 64 + rt * 16 + l15;
      const float4* p = reinterpret_cast<const float4*>(st + (size_t)row * S + ks * 32 + q * 8);
      float4 x = p[0], y = p[1];
      union { bf16x8 v; unsigned short u[8]; } a;
      a.u[0] = f2bf(x.x); a.u[1] = f2bf(x.y); a.u[2] = f2bf(x.z); a.u[3] = f2bf(x.w);
      a.u[4] = f2bf(y.x); a.u[5] = f2bf(y.y); a.u[6] = f2bf(y.z); a.u[7] = f2bf(y.w);
      aA[rt][ks] = a.v;
    }

  // ---- preload ALL scalar globals now (older than any DMA in vmcnt FIFO) ----
  float pb1[4][4];
  #pragma unroll
  for (int cc = 0; cc < 4; ++cc)
    #pragma unroll
    for (int ctl = 0; ctl < 4; ++ctl)
      pb1[cc][ctl] = b1[c * HD + (cc * 4 + ctl) * 16 + l15];
  float pb2[8][2], pw3[8][2];
  #pragma unroll
  for (int ch = 0; ch < 8; ++ch)
    #pragma unroll
    for (int ct = 0; ct < 2; ++ct) {
      const int n = ch * 32 + ct * 16 + l15;
      pb2[ch][ct] = b2[c * HD + n];
      pw3[ch][ct] = W3[c * HD + n];
    }
  const float bb3 = b3[c];

  // ---- phase 1: 4 quarters of 64 h1-cols; B-frags direct from W1T (L2-hot) ----
  bf16x8 aF[4][4][2];  // [cc][rt][k2] h1 A-fragments, register/AGPR-resident
  bool dma_started = false;
  #pragma unroll
  for (int cc = 0; cc < 4; ++cc) {
    f32x4 acc[4][4];
    #pragma unroll
    for (int rt = 0; rt < 4; ++rt)
      #pragma unroll
      for (int ctl = 0; ctl < 4; ++ctl)
        acc[rt][ctl] = (f32x4){0.f, 0.f, 0.f, 0.f};

    #pragma unroll
    for (int ks = 0; ks < 2; ++ks) {
      const int koff = ks * 32 + q * 8;
      bf16x8 bq[4];
      #pragma unroll
      for (int ctl = 0; ctl < 4; ++ctl)
        bq[ctl] = *reinterpret_cast<const bf16x8*>(
            W1c + ((cc * 4 + ctl) * 16 + l15) * S + koff);

      // DMA prologue for W2 chunks 0,1 — issued AFTER quarter-0's B-loads so
      // the first MFMA's vmcnt wait does not cover the DMAs (FIFO).
      if (cc == 0 && ks == 0 && !dma_started) {
        dma_started = true;
        #pragma unroll
        for (int pc = 0; pc < 2; ++pc) {
          unsigned short* buf = sW2 + pc * (32 * 256);
          #pragma unroll
          for (int i = 0; i < 4; ++i) {
            const int b2i = wv * 4 + i;            // 1KB unit 0..15 (2 rows each)
            const int r   = b2i * 2 + (lane >> 5); // local row 0..31
            const int p   = lane & 31;             // phys granule
            const int j   = p ^ (r & 7);           // logical granule
            gl2lds16(W2c + (pc * 32 + r) * 256 + j * 8, buf + b2i * 512);
          }
        }
      }

      #pragma unroll
      for (int ctl = 0; ctl < 4; ++ctl)
        #pragma unroll
        for (int rt = 0; rt < 4; ++rt)
          acc[rt][ctl] = __builtin_amdgcn_mfma_f32_16x16x32_bf16(
              aA[rt][ks], bq[ctl], acc[rt][ctl], 0, 0, 0);
    }

    // bias+relu; C-layout -> A-layout through this wave's OWN sT rows
    // (rows [wv*64, wv*64+64) touched only by wave wv -> lgkmcnt drain, no barrier)
    #pragma unroll
    for (int rt = 0; rt < 4; ++rt) {
      const int rbase = wv * 64 + rt * 16 + q * 4;
      #pragma unroll
      for (int ctl = 0; ctl < 4; ++ctl) {
        const float bias = pb1[cc][ctl];
        #pragma unroll
        for (int r = 0; r < 4; ++r) {
          float v = acc[rt][ctl][r] + bias;
          v = v > 0.f ? v : 0.f;
          sT[(rbase + r) * LDT + ctl * 16 + l15] = f2bf(v);
        }
      }
    }
    __asm__ __volatile__("s_waitcnt lgkmcnt(0)" ::: "memory");
    #pragma unroll
    for (int rt = 0; rt < 4; ++rt)
      #pragma unroll
      for (int k2 = 0; k2 < 2; ++k2)
        aF[cc][rt][k2] = *reinterpret_cast<const bf16x8*>(
            sT + (wv * 64 + rt * 16 + l15) * LDT + k2 * 32 + q * 8);
    __asm__ __volatile__("s_waitcnt lgkmcnt(0)" ::: "memory");  // WAR guard
  }

  __syncthreads();   // drains vmcnt(0): chunks 0,1 landed; all waves ready

  // ---- phase 2+3: d = relu(h1 @ W2 + b2) . W3, chunk ping-pong ----
  // Steady state: no global register loads inside the loop -> the only vmcnt
  // drain is the per-chunk barrier, whose pending DMA was issued a full
  // chunk-compute (~64 MFMAs) earlier.
  float dacc[4][4];
  #pragma unroll
  for (int rt = 0; rt < 4; ++rt)
    #pragma unroll
    for (int r = 0; r < 4; ++r) dacc[rt][r] = 0.f;

  #pragma unroll
  for (int ch = 0; ch < 8; ++ch) {
    const unsigned short* buf = sW2 + (ch & 1) * (32 * 256);

    f32x4 acc[4][2];
    #pragma unroll
    for (int rt = 0; rt < 4; ++rt)
      #pragma unroll
      for (int ct = 0; ct < 2; ++ct)
        acc[rt][ct] = (f32x4){0.f, 0.f, 0.f, 0.f};

    #pragma unroll
    for (int ks = 0; ks < 8; ++ks) {
      const int jj = ks * 4 + q;            // logical granule of this k-slice
      const int cc = ks >> 1, k2 = ks & 1;
      #pragma unroll
      for (int ct = 0; ct < 2; ++ct) {
        const int nl = ct * 16 + l15;       // local row (= h2 col within chunk)
        bf16x8 b = *reinterpret_cast<const bf16x8*>(
            buf + nl * 256 + ((jj ^ (l15 & 7)) << 3));
        #pragma unroll
        for (int rt = 0; rt < 4; ++rt)
          acc[rt][ct] = __builtin_amdgcn_mfma_f32_16x16x32_bf16(
              aF[cc][rt][k2], b, acc[rt][ct], 0, 0, 0);
      }
    }

    // fused epilogue: relu(h2 + b2) dot W3 per row (all operands in regs)
    #pragma unroll
    for (int ct = 0; ct < 2; ++ct) {
      const float bias = pb2[ch][ct];
      const float w3v  = pw3[ch][ct];
      #pragma unroll
      for (int rt = 0; rt < 4; ++rt)
        #pragma unroll
        for (int r = 0; r < 4; ++r) {
          float v = acc[rt][ct][r] + bias;
          v = v > 0.f ? v : 0.f;
          dacc[rt][r] += v * w3v;
        }
    }

    __syncthreads();   // readers of buf[ch&1] done; drains DMA of chunk ch+1's buffer
    if (ch < 6) {      // refill the buffer just freed with chunk ch+2
      unsigned short* nbuf = sW2 + (ch & 1) * (32 * 256);
      #pragma unroll
      for (int i = 0; i < 4; ++i) {
        const int b2i = wv * 4 + i;
        const int r   = b2i * 2 + (lane >> 5);
        const int p   = lane & 31;
        const int j   = p ^ (r & 7);
        gl2lds16(W2c + ((ch + 2) * 32 + r) * 256 + j * 8, nbuf + b2i * 512);
      }
    }
  }

  // ---- reduce over the 16 col-lanes, write out ----
  #pragma unroll
  for (int rt = 0; rt < 4; ++rt)
    #pragma unroll
    for (int r = 0; r < 4; ++r) {
      float v = dacc[rt][r];
      v += __shfl_xor(v, 1);
      v += __shfl_xor(v, 2);
      v += __shfl_xor(v, 4);
      v += __shfl_xor(v, 8);
      dacc[rt][r] = v;
    }

  if (l15 == 0) {
    const int rbase = row0 + wv * 64 + q * 4;
    #pragma unroll
    for (int rt = 0; rt < 4; ++rt)
      #pragma unroll
      for (int r = 0; r < 4; ++r)
        out[(rbase + rt * 16 + r) * C + c] = dacc[rt][r] + bb3;
  }
}

extern "C" void kernel_launch(void* const* d_in, const int* in_sizes, int n_in,
                              void* d_out, int out_size, void* d_ws, size_t ws_size,
                              hipStream_t stream)
{
  const float* st = (const float*)d_in[0];
  const float* W1 = (const float*)d_in[1];
  const float* b1 = (const float*)d_in[2];
  const float* W2 = (const float*)d_in[3];
  const float* b2 = (const float*)d_in[4];
  const float* W3 = (const float*)d_in[5];
  const float* b3 = (const float*)d_in[6];
  float* out = (float*)d_out;

  unsigned short* W1T = (unsigned short*)d_ws;         // 131072 bf16
  unsigned short* W2T = W1T + C * HD * S;              // 524288 bf16

  prep_weights<<<dim3(640), dim3(256), 0, stream>>>(W1, W2, W1T, W2T);
  moe_fused<<<dim3(2048), dim3(256), 0, stream>>>(st, W1T, W2T, b1, b2, W3, b3, out);
}